// Round 2
// baseline (877.586 us; speedup 1.0000x reference)
//
#include <hip/hip_runtime.h>
#include <math.h>

// SSIM loss fp32, B=64 H=W=512, 11x11 Gaussian sigma=1.5 (separable w ⊗ w).
// LDS-free design: each wave owns a 64-col slab (outputs = middle 54 cols) and
// a 22-row strip. Vertical 11-tap conv from global via register circular window
// (slot = row mod 11); horizontal 11-tap via ds_bpermute across the wave64.
// Per-block partial sums -> d_ws; tiny fin kernel reduces 3840 partials.

#define OUTW   54            // output cols per wave (lanes 5..58)
#define RR     22            // output rows per wave (2 x 11 phases)
#define NTILX  10            // ceil(512/54)
#define NBY    6             // 24 strips / 4 waves per block
#define NBLK   (NTILX * NBY * 64)   // 3840

struct W11 { float w[11]; };

__device__ __forceinline__ float bperm(int addr, float v) {
    return __int_as_float(__builtin_amdgcn_ds_bpermute(addr, __float_as_int(v)));
}

__global__ __launch_bounds__(256) void ssim_main(
    const float* __restrict__ x, const float* __restrict__ y,
    float* __restrict__ partial, W11 wk)
{
    const int tid  = threadIdx.x;
    const int lane = tid & 63;
    const int wv   = tid >> 6;
    const int strip = blockIdx.y * 4 + wv;          // 0..23
    const int r0   = strip * RR;                    // first output row
    const int c    = blockIdx.x * OUTW - 5 + lane;  // this lane's column
    const bool colOK = (unsigned)c < 512u;
    const float* __restrict__ xb = x + (size_t)blockIdx.z * (512 * 512);
    const float* __restrict__ yb = y + (size_t)blockIdx.z * (512 * 512);

    // precomputed bpermute byte addresses for lane +/- d
    int aL[5], aR[5];
    #pragma unroll
    for (int d = 1; d <= 5; ++d) { aL[d-1] = (lane - d) << 2; aR[d-1] = (lane + d) << 2; }

    // circular window: wx[s]/wy[s] hold input row r with (r mod 11) == s
    float wx[11], wy[11];
    #pragma unroll
    for (int k = 0; k < 10; ++k) {              // rows r0-5 .. r0+4
        int r = r0 - 5 + k;
        float nx = 0.f, ny = 0.f;
        if (colOK && (unsigned)r < 512u) {
            nx = xb[r * 512 + c];
            ny = yb[r * 512 + c];
        }
        wx[(6 + k) % 11] = nx;
        wy[(6 + k) % 11] = ny;
    }

    const bool colValid = (lane >= 5) && (lane <= 58) && colOK;
    const int  rleft = 512 - r0;                // valid output rows this strip
    const float C1 = 1e-4f, C2 = 9e-4f;
    float lsum = 0.f;

    #pragma unroll 1
    for (int m = 0; m < 2; ++m) {
        #pragma unroll
        for (int p = 0; p < 11; ++p) {
            const int ph = m * 11 + p;          // row offset within strip
            const int rl = r0 + ph + 5;         // input row to bring in
            const int sl = (p + 5) % 11;        // its slot (rl mod 11)
            float nx = 0.f, ny = 0.f;
            if (colOK && rl < 512) {
                nx = xb[rl * 512 + c];
                ny = yb[rl * 512 + c];
            }
            wx[sl] = nx;
            wy[sl] = ny;

            // vertical 11-tap conv of {x, y, x^2, y^2, xy}
            float vx = 0.f, vy = 0.f, vxx = 0.f, vyy = 0.f, vxy = 0.f;
            #pragma unroll
            for (int s = 0; s < 11; ++s) {
                const int j = (s - p + 16) % 11;   // weight index, compile-time
                const float wj = wk.w[j];
                const float xs = wx[s], ys = wy[s];
                const float tx = wj * xs, ty = wj * ys;
                vx += tx;  vy += ty;
                vxx = fmaf(tx, xs, vxx);
                vyy = fmaf(ty, ys, vyy);
                vxy = fmaf(tx, ys, vxy);
            }

            // horizontal 11-tap across lanes (symmetric weights)
            float hx  = wk.w[5] * vx,  hy  = wk.w[5] * vy;
            float hxx = wk.w[5] * vxx, hyy = wk.w[5] * vyy, hxy = wk.w[5] * vxy;
            #pragma unroll
            for (int d = 1; d <= 5; ++d) {
                const float wd = wk.w[5 - d];
                hx  = fmaf(wd, bperm(aL[d-1], vx)  + bperm(aR[d-1], vx),  hx);
                hy  = fmaf(wd, bperm(aL[d-1], vy)  + bperm(aR[d-1], vy),  hy);
                hxx = fmaf(wd, bperm(aL[d-1], vxx) + bperm(aR[d-1], vxx), hxx);
                hyy = fmaf(wd, bperm(aL[d-1], vyy) + bperm(aR[d-1], vyy), hyy);
                hxy = fmaf(wd, bperm(aL[d-1], vxy) + bperm(aR[d-1], vxy), hxy);
            }

            // SSIM at this pixel
            const float mx2 = hx * hx, my2 = hy * hy, mxy = hx * hy;
            const float sx2 = hxx - mx2, sy2 = hyy - my2, sxy = hxy - mxy;
            const float num = (2.f * mxy + C1) * (2.f * sxy + C2);
            const float den = (mx2 + my2 + C1) * (sx2 + sy2 + C2) + 1e-12f;
            const float v = num * __builtin_amdgcn_rcpf(den);
            if (colValid && ph < rleft) lsum += v;
        }
    }

    // wave reduce, then block partial
    #pragma unroll
    for (int off = 32; off; off >>= 1) lsum += __shfl_down(lsum, off);
    __shared__ float red[4];
    if (lane == 0) red[wv] = lsum;
    __syncthreads();
    if (tid == 0)
        partial[((int)blockIdx.z * NBY + (int)blockIdx.y) * NTILX + (int)blockIdx.x] =
            red[0] + red[1] + red[2] + red[3];
}

__global__ __launch_bounds__(256) void ssim_fin(const float* __restrict__ partial,
                                                float* __restrict__ out) {
    float s = 0.f;
    for (int i = threadIdx.x; i < NBLK; i += 256) s += partial[i];
    #pragma unroll
    for (int off = 32; off; off >>= 1) s += __shfl_down(s, off);
    __shared__ float red[4];
    if ((threadIdx.x & 63) == 0) red[threadIdx.x >> 6] = s;
    __syncthreads();
    if (threadIdx.x == 0)
        out[0] = 1.0f - (red[0] + red[1] + red[2] + red[3]) * (1.0f / 16777216.0f);
}

extern "C" void kernel_launch(void* const* d_in, const int* in_sizes, int n_in,
                              void* d_out, int out_size, void* d_ws, size_t ws_size,
                              hipStream_t stream) {
    const float* x = (const float*)d_in[0];
    const float* y = (const float*)d_in[1];
    float* out = (float*)d_out;
    float* partial = (float*)d_ws;

    // 1D Gaussian, sigma=1.5, ks=11, normalized (2D kernel = w ⊗ w exactly)
    W11 wk;
    double e[11], s = 0.0;
    for (int i = 0; i < 11; ++i) {
        double d = (double)i - 5.0;
        e[i] = exp(-(d * d) / 4.5);
        s += e[i];
    }
    for (int i = 0; i < 11; ++i) wk.w[i] = (float)(e[i] / s);

    hipLaunchKernelGGL(ssim_main, dim3(NTILX, NBY, 64), dim3(256), 0, stream,
                       x, y, partial, wk);
    hipLaunchKernelGGL(ssim_fin, dim3(1), dim3(256), 0, stream, partial, out);
}

// Round 4
// 282.781 us; speedup vs baseline: 3.1034x; 3.1034x over previous
//
#include <hip/hip_runtime.h>
#include <math.h>

// SSIM loss fp32, B=64 H=W=512, 11x11 Gaussian sigma=1.5, separable (w ⊗ w).
// Per block: 32-wide x 64-high output tile as 2 subtiles of 32x32.
// Stage 2 (no raw staging): each task = 1 input row x 4 output cols; loads its
//   20-float window straight from global (5 aligned float4 on interior path),
//   computes horizontal 11-tap conv of {x,y,x2,y2,xy}, writes h COLUMN-MAJOR
//   (stride 42) -> 2-way LDS bank aliasing only (free).
// Stage 3: vertical 11-tap conv from h via contiguous ds_read_b64 + SSIM.
// LDS = 5*32*42*4 = 26.9 KB -> 6 blocks/CU (vs R1's 3). Partials -> d_ws.

#define TS     32
#define INROWS 42
#define HSTR   42
#define SUBT   2
#define GX     16
#define GY     8
#define NPART  (64 * GY * GX)   // 8192 partials, 32 KB

struct W11 { float w[11]; };

__device__ __forceinline__ void accum_tap(int k, float xv, float yv,
    float* hx, float* hy, float* hxx, float* hyy, float* hxy, const W11& wk)
{
    #pragma unroll
    for (int o = 0; o < 4; ++o) {
        const int j = k - 3 - o;           // compile-time
        if (j < 0 || j > 10) continue;
        const float wj = wk.w[j];
        const float tx = wj * xv, ty = wj * yv;
        hx[o] += tx;  hy[o] += ty;
        hxx[o] = fmaf(tx, xv, hxx[o]);
        hyy[o] = fmaf(ty, yv, hyy[o]);
        hxy[o] = fmaf(tx, yv, hxy[o]);
    }
}

template<bool BORDER>
__device__ __forceinline__ void stage2(const float* __restrict__ xb,
    const float* __restrict__ yb, int ox, int oy, int tid,
    float (*h)[TS * HSTR], const W11& wk)
{
    for (int t = tid; t < INROWS * 8; t += 256) {
        const int r  = t >> 3;             // input row within tile, 0..41
        const int c0 = (t & 7) << 2;       // first output col, 0..28
        const int gr  = oy - 5 + r;
        const int gc0 = ox + c0 - 8;       // 16B-aligned on interior path
        float hx[4]  = {0.f,0.f,0.f,0.f};
        float hy[4]  = {0.f,0.f,0.f,0.f};
        float hxx[4] = {0.f,0.f,0.f,0.f};
        float hyy[4] = {0.f,0.f,0.f,0.f};
        float hxy[4] = {0.f,0.f,0.f,0.f};

        if (!BORDER) {
            const float4* px = (const float4*)(xb + gr * 512 + gc0);
            const float4* py = (const float4*)(yb + gr * 512 + gc0);
            #pragma unroll
            for (int kk = 0; kk < 5; ++kk) {
                const float4 fx = px[kk], fy = py[kk];
                const float ex[4] = {fx.x, fx.y, fx.z, fx.w};
                const float ey[4] = {fy.x, fy.y, fy.z, fy.w};
                #pragma unroll
                for (int e = 0; e < 4; ++e) {
                    const int k = kk * 4 + e;
                    if (k < 3 || k > 16) continue;   // window uses k=3..16
                    accum_tap(k, ex[e], ey[e], hx, hy, hxx, hyy, hxy, wk);
                }
            }
        } else {
            const int grc = min(max(gr, 0), 511);
            const bool rok = (unsigned)gr < 512u;
            #pragma unroll
            for (int k = 3; k <= 16; ++k) {
                const int gc  = gc0 + k;
                const int gcc = min(max(gc, 0), 511);
                const bool ok = rok && ((unsigned)gc < 512u);
                float xv = xb[grc * 512 + gcc];
                float yv = yb[grc * 512 + gcc];
                if (!ok) { xv = 0.f; yv = 0.f; }
                accum_tap(k, xv, yv, hx, hy, hxx, hyy, hxy, wk);
            }
        }

        #pragma unroll
        for (int o = 0; o < 4; ++o) {
            const int idx = (c0 + o) * HSTR + r;   // column-major
            h[0][idx] = hx[o];
            h[1][idx] = hy[o];
            h[2][idx] = hxx[o];
            h[3][idx] = hyy[o];
            h[4][idx] = hxy[o];
        }
    }
}

__global__ __launch_bounds__(256) void ssim_main(
    const float* __restrict__ x, const float* __restrict__ y,
    float* __restrict__ partial, W11 wk, int atomic_mode)
{
    __shared__ __align__(16) float h[5][TS * HSTR];
    __shared__ float red[4];

    const int tid = threadIdx.x;
    const int bx = blockIdx.x, by = blockIdx.y, bz = blockIdx.z;
    const float* __restrict__ xb = x + (size_t)bz * (512 * 512);
    const float* __restrict__ yb = y + (size_t)bz * (512 * 512);
    const int ox = bx * TS;
    const float C1 = 1e-4f, C2 = 9e-4f;
    float lsum = 0.f;

    #pragma unroll 1
    for (int s = 0; s < SUBT; ++s) {
        const int byy = by * SUBT + s;
        const int oy  = byy * TS;
        const bool interior = (bx >= 1) && (bx <= 14) && (byy >= 1) && (byy <= 14);
        if (interior) stage2<false>(xb, yb, ox, oy, tid, h, wk);
        else          stage2<true >(xb, yb, ox, oy, tid, h, wk);
        __syncthreads();

        // stage 3: vertical conv + SSIM, one thread = 4 stacked output rows
        const int c  = tid & 31;
        const int r0 = (tid >> 5) << 2;          // 0,4,..,28
        float sq[5][4];
        #pragma unroll
        for (int q = 0; q < 5; ++q) {
            const float2* p = (const float2*)&h[q][c * HSTR + r0];
            float tv[14];
            #pragma unroll
            for (int kk = 0; kk < 7; ++kk) {
                const float2 v = p[kk];
                tv[2 * kk] = v.x; tv[2 * kk + 1] = v.y;
            }
            #pragma unroll
            for (int o = 0; o < 4; ++o) {
                float a = 0.f;
                #pragma unroll
                for (int j = 0; j < 11; ++j) a = fmaf(wk.w[j], tv[o + j], a);
                sq[q][o] = a;
            }
        }
        #pragma unroll
        for (int o = 0; o < 4; ++o) {
            const float mx = sq[0][o], my = sq[1][o];
            const float mx2 = mx * mx, my2 = my * my, mxy = mx * my;
            const float sx2 = sq[2][o] - mx2;
            const float sy2 = sq[3][o] - my2;
            const float sxy = sq[4][o] - mxy;
            const float num = (2.f * mxy + C1) * (2.f * sxy + C2);
            const float den = (mx2 + my2 + C1) * (sx2 + sy2 + C2) + 1e-12f;
            lsum += num * __builtin_amdgcn_rcpf(den);
        }
        __syncthreads();   // protect h before next subtile overwrites
    }

    #pragma unroll
    for (int off = 32; off; off >>= 1) lsum += __shfl_down(lsum, off);
    if ((tid & 63) == 0) red[tid >> 6] = lsum;
    __syncthreads();
    if (tid == 0) {
        const float v = red[0] + red[1] + red[2] + red[3];
        if (atomic_mode) atomicAdd(partial, v);
        else partial[(bz * GY + by) * GX + bx] = v;
    }
}

__global__ __launch_bounds__(256) void ssim_fin(const float* __restrict__ partial,
                                                float* __restrict__ out, int n)
{
    float s = 0.f;
    for (int i = threadIdx.x; i < n; i += 256) s += partial[i];
    #pragma unroll
    for (int off = 32; off; off >>= 1) s += __shfl_down(s, off);
    __shared__ float red[4];
    if ((threadIdx.x & 63) == 0) red[threadIdx.x >> 6] = s;
    __syncthreads();
    if (threadIdx.x == 0)
        out[0] = 1.0f - (red[0] + red[1] + red[2] + red[3]) * (1.0f / 16777216.0f);
}

extern "C" void kernel_launch(void* const* d_in, const int* in_sizes, int n_in,
                              void* d_out, int out_size, void* d_ws, size_t ws_size,
                              hipStream_t stream) {
    const float* x = (const float*)d_in[0];
    const float* y = (const float*)d_in[1];
    float* out = (float*)d_out;
    float* ws  = (float*)d_ws;

    W11 wk;
    double e[11], s = 0.0;
    for (int i = 0; i < 11; ++i) {
        double d = (double)i - 5.0;
        e[i] = exp(-(d * d) / 4.5);
        s += e[i];
    }
    for (int i = 0; i < 11; ++i) wk.w[i] = (float)(e[i] / s);

    const bool use_partial = ws_size >= (size_t)NPART * sizeof(float);
    if (!use_partial) hipMemsetAsync(d_ws, 0, sizeof(float), stream);

    hipLaunchKernelGGL(ssim_main, dim3(GX, GY, 64), dim3(256), 0, stream,
                       x, y, ws, wk, use_partial ? 0 : 1);
    hipLaunchKernelGGL(ssim_fin, dim3(1), dim3(256), 0, stream,
                       ws, out, use_partial ? NPART : 1);
}

// Round 6
// 275.963 us; speedup vs baseline: 3.1801x; 1.0247x over previous
//
#include <hip/hip_runtime.h>
#include <math.h>

// SSIM loss fp32, B=64 H=W=512, 11x11 Gaussian sigma=1.5, separable (w ⊗ w).
// R5: packed-fp32 design. Block = 32-col x 64-row tile; the two 32-row halves
// ride in the two lanes of a float2 ext-vector -> v_pk_fma_f32 dual-issue.
// Stage 2: 336 tasks (42 h-rows x 8 col-groups), each loads its 20-float
//   window per band via aligned float4 (interior) or clamped+masked scalars
//   (x-border blocks), precomputes xx/yy/xy, runs 5 pure 11-tap horizontal
//   convs, writes h (float2, col-major stride 42) to LDS.
// Stage 3: vertical 11-tap convs via b128 LDS reads + packed SSIM.
// One syncthreads pair total. 8192 partials -> d_ws; fin reduces.

typedef float v2f __attribute__((ext_vector_type(2)));

#define TS   32
#define HR   42
#define GX   16
#define GY   8
#define NPART (64 * GY * GX)   // 8192

struct W11 { float w[11]; };

__global__ __launch_bounds__(256) void ssim_main(
    const float* __restrict__ x, const float* __restrict__ y,
    float* __restrict__ partial, W11 wk, int atomic_mode)
{
    __shared__ __align__(16) v2f hst[5][TS * HR];   // 53760 B
    __shared__ float red[4];

    const int tid = threadIdx.x;
    const int bx = blockIdx.x, by = blockIdx.y, bz = blockIdx.z;
    const float* __restrict__ xb = x + (size_t)bz * (512 * 512);
    const float* __restrict__ yb = y + (size_t)bz * (512 * 512);
    const int ox = bx * TS;
    const int oy = by * 64;
    const bool colInterior = (bx >= 1) && (bx <= 14);

    // ---- stage 2: horizontal convs of {x,y,xx,yy,xy}, both bands packed ----
    for (int t = tid; t < HR * 8; t += 256) {
        const int r  = t >> 3;
        const int c0 = (t & 7) << 2;
        const int gr = oy - 5 + r;              // band0 input row
        const float m0 = ((unsigned)gr        < 512u) ? 1.f : 0.f;
        const float m1 = ((unsigned)(gr + 32) < 512u) ? 1.f : 0.f;
        const v2f  m  = (v2f){m0, m1};
        const int grc0 = min(max(gr, 0), 511);
        const int grc1 = min(max(gr + 32, 0), 511);
        const int gc0 = ox + c0 - 8;            // window col k=3..16 used

        v2f wxv[14], wyv[14];
        if (colInterior) {
            const float4* px0 = (const float4*)(xb + grc0 * 512 + gc0);
            const float4* px1 = (const float4*)(xb + grc1 * 512 + gc0);
            const float4* py0 = (const float4*)(yb + grc0 * 512 + gc0);
            const float4* py1 = (const float4*)(yb + grc1 * 512 + gc0);
            #pragma unroll
            for (int kk = 0; kk < 5; ++kk) {
                const float4 a0 = px0[kk], a1 = px1[kk];
                const float4 b0 = py0[kk], b1 = py1[kk];
                const float ea0[4] = {a0.x, a0.y, a0.z, a0.w};
                const float ea1[4] = {a1.x, a1.y, a1.z, a1.w};
                const float eb0[4] = {b0.x, b0.y, b0.z, b0.w};
                const float eb1[4] = {b1.x, b1.y, b1.z, b1.w};
                #pragma unroll
                for (int e = 0; e < 4; ++e) {
                    const int k = kk * 4 + e;
                    if (k < 3 || k > 16) continue;
                    wxv[k - 3] = (v2f){ea0[e], ea1[e]} * m;
                    wyv[k - 3] = (v2f){eb0[e], eb1[e]} * m;
                }
            }
        } else {
            #pragma unroll
            for (int k = 3; k <= 16; ++k) {
                const int gc  = gc0 + k;
                const int gcc = min(max(gc, 0), 511);
                const float cm = ((unsigned)gc < 512u) ? 1.f : 0.f;
                const v2f mm = m * cm;
                wxv[k - 3] = (v2f){xb[grc0 * 512 + gcc], xb[grc1 * 512 + gcc]} * mm;
                wyv[k - 3] = (v2f){yb[grc0 * 512 + gcc], yb[grc1 * 512 + gcc]} * mm;
            }
        }

        v2f hx[4], hy[4], hxx[4], hyy[4], hxy[4];
        #pragma unroll
        for (int o = 0; o < 4; ++o) {
            hx[o] = (v2f)0.f; hy[o] = (v2f)0.f;
            hxx[o] = (v2f)0.f; hyy[o] = (v2f)0.f; hxy[o] = (v2f)0.f;
        }
        #pragma unroll
        for (int i = 0; i < 14; ++i) {
            const v2f xv = wxv[i], yv = wyv[i];
            const v2f xx = xv * xv, yy = yv * yv, xy = xv * yv;
            #pragma unroll
            for (int o = 0; o < 4; ++o) {
                const int j = i - o;            // compile-time
                if (j < 0 || j > 10) continue;
                const float wj = wk.w[j];
                hx[o]  += wj * xv;
                hy[o]  += wj * yv;
                hxx[o] += wj * xx;
                hyy[o] += wj * yy;
                hxy[o] += wj * xy;
            }
        }
        #pragma unroll
        for (int o = 0; o < 4; ++o) {
            const int idx = (c0 + o) * HR + r;
            hst[0][idx] = hx[o];
            hst[1][idx] = hy[o];
            hst[2][idx] = hxx[o];
            hst[3][idx] = hyy[o];
            hst[4][idx] = hxy[o];
        }
    }
    __syncthreads();

    // ---- stage 3: vertical convs + SSIM, thread = 1 col x 4 row-pairs ----
    const int c  = tid & 31;
    const int r0 = (tid >> 5) << 2;             // 0..28, even -> 16B aligned
    v2f sq[5][4];
    #pragma unroll
    for (int q = 0; q < 5; ++q) {
        const float4* p4 = (const float4*)&hst[q][c * HR + r0];
        v2f tv[14];
        #pragma unroll
        for (int kk = 0; kk < 7; ++kk) {
            const float4 v = p4[kk];
            tv[2 * kk]     = (v2f){v.x, v.y};
            tv[2 * kk + 1] = (v2f){v.z, v.w};
        }
        #pragma unroll
        for (int o = 0; o < 4; ++o) {
            v2f a = (v2f)0.f;
            #pragma unroll
            for (int j = 0; j < 11; ++j) a += wk.w[j] * tv[o + j];
            sq[q][o] = a;
        }
    }

    const float C1 = 1e-4f, C2 = 9e-4f;
    float lsum = 0.f;
    #pragma unroll
    for (int o = 0; o < 4; ++o) {
        const v2f mx = sq[0][o], my = sq[1][o];
        const v2f mx2 = mx * mx, my2 = my * my, mxy = mx * my;
        const v2f sx2 = sq[2][o] - mx2;
        const v2f sy2 = sq[3][o] - my2;
        const v2f sxy = sq[4][o] - mxy;
        const v2f num = (2.f * mxy + C1) * (2.f * sxy + C2);
        const v2f den = (mx2 + my2 + C1) * (sx2 + sy2 + C2) + 1e-12f;
        lsum += num.x * __builtin_amdgcn_rcpf(den.x)
              + num.y * __builtin_amdgcn_rcpf(den.y);
    }

    // ---- block reduction ----
    #pragma unroll
    for (int off = 32; off; off >>= 1) lsum += __shfl_down(lsum, off);
    if ((tid & 63) == 0) red[tid >> 6] = lsum;
    __syncthreads();
    if (tid == 0) {
        const float v = red[0] + red[1] + red[2] + red[3];
        if (atomic_mode) atomicAdd(partial, v);
        else partial[(bz * GY + by) * GX + bx] = v;
    }
}

__global__ __launch_bounds__(256) void ssim_fin(const float* __restrict__ partial,
                                                float* __restrict__ out, int n)
{
    float s = 0.f;
    for (int i = threadIdx.x; i < n; i += 256) s += partial[i];
    #pragma unroll
    for (int off = 32; off; off >>= 1) s += __shfl_down(s, off);
    __shared__ float red[4];
    if ((threadIdx.x & 63) == 0) red[threadIdx.x >> 6] = s;
    __syncthreads();
    if (threadIdx.x == 0)
        out[0] = 1.0f - (red[0] + red[1] + red[2] + red[3]) * (1.0f / 16777216.0f);
}

extern "C" void kernel_launch(void* const* d_in, const int* in_sizes, int n_in,
                              void* d_out, int out_size, void* d_ws, size_t ws_size,
                              hipStream_t stream) {
    const float* x = (const float*)d_in[0];
    const float* y = (const float*)d_in[1];
    float* out = (float*)d_out;
    float* ws  = (float*)d_ws;

    W11 wk;
    double e[11], s = 0.0;
    for (int i = 0; i < 11; ++i) {
        double d = (double)i - 5.0;
        e[i] = exp(-(d * d) / 4.5);
        s += e[i];
    }
    for (int i = 0; i < 11; ++i) wk.w[i] = (float)(e[i] / s);

    const bool use_partial = ws_size >= (size_t)NPART * sizeof(float);
    if (!use_partial) hipMemsetAsync(d_ws, 0, sizeof(float), stream);

    hipLaunchKernelGGL(ssim_main, dim3(GX, GY, 64), dim3(256), 0, stream,
                       x, y, ws, wk, use_partial ? 0 : 1);
    hipLaunchKernelGGL(ssim_fin, dim3(1), dim3(256), 0, stream,
                       ws, out, use_partial ? NPART : 1);
}

// Round 7
// 250.839 us; speedup vs baseline: 3.4986x; 1.1002x over previous
//
#include <hip/hip_runtime.h>
#include <math.h>

// SSIM loss fp32, B=64 H=W=512, 11x11 Gaussian sigma=1.5, separable (w ⊗ w).
// R7: packed-fp32 + 4-array LDS + 512-thread blocks.
// Key algebra: SSIM uses only (sigma_x2 + sigma_y2), never separately ->
// stage 2 stores 4 conv quantities {x, y, x^2+y^2, x*y} (not 5).
// Block = 32-col x 64-row tile; row bands (r, r+32) ride in v2f lanes
// (v_pk_fma_f32). LDS = 4 * 32*42 * 8 = 43 KB -> 3 blocks/CU, 8 waves/block
// -> 24-wave/CU residency cap (75%) vs R6's 25%.
// Stage 2: 336 tasks (42 input rows x 8 col-groups), one conditional round.
// Stage 3: 512 tasks (32 cols x 16 row-pair-groups, 2 packed rows each).

typedef float v2f __attribute__((ext_vector_type(2)));

#define TS   32
#define HR   42
#define GX   16
#define GY   8
#define NPART (64 * GY * GX)   // 8192

struct W11 { float w[11]; };

__global__ __launch_bounds__(512) void ssim_main(
    const float* __restrict__ x, const float* __restrict__ y,
    float* __restrict__ partial, W11 wk, int atomic_mode)
{
    __shared__ __align__(16) v2f hst[4][TS * HR];   // 43008 B
    __shared__ float red[8];

    const int tid = threadIdx.x;
    const int bx = blockIdx.x, by = blockIdx.y, bz = blockIdx.z;
    const float* __restrict__ xb = x + (size_t)bz * (512 * 512);
    const float* __restrict__ yb = y + (size_t)bz * (512 * 512);
    const int ox = bx * TS;
    const int oy = by * 64;
    const bool colInterior = (bx >= 1) && (bx <= 14);

    // ---- stage 2: horizontal convs of {x, y, x^2+y^2, xy}, bands packed ----
    if (tid < HR * 8) {
        const int r  = tid >> 3;
        const int c0 = (tid & 7) << 2;
        const int gr = oy - 5 + r;              // band0 input row
        const float m0 = ((unsigned)gr        < 512u) ? 1.f : 0.f;
        const float m1 = ((unsigned)(gr + 32) < 512u) ? 1.f : 0.f;
        const v2f  m  = (v2f){m0, m1};
        const int grc0 = min(max(gr, 0), 511);
        const int grc1 = min(max(gr + 32, 0), 511);
        const int gc0 = ox + c0 - 8;            // window cols k=3..16 used

        v2f wxv[14], wyv[14];
        if (colInterior) {
            const float4* px0 = (const float4*)(xb + grc0 * 512 + gc0);
            const float4* px1 = (const float4*)(xb + grc1 * 512 + gc0);
            const float4* py0 = (const float4*)(yb + grc0 * 512 + gc0);
            const float4* py1 = (const float4*)(yb + grc1 * 512 + gc0);
            #pragma unroll
            for (int kk = 0; kk < 5; ++kk) {
                const float4 a0 = px0[kk], a1 = px1[kk];
                const float4 b0 = py0[kk], b1 = py1[kk];
                const float ea0[4] = {a0.x, a0.y, a0.z, a0.w};
                const float ea1[4] = {a1.x, a1.y, a1.z, a1.w};
                const float eb0[4] = {b0.x, b0.y, b0.z, b0.w};
                const float eb1[4] = {b1.x, b1.y, b1.z, b1.w};
                #pragma unroll
                for (int e = 0; e < 4; ++e) {
                    const int k = kk * 4 + e;
                    if (k < 3 || k > 16) continue;
                    wxv[k - 3] = (v2f){ea0[e], ea1[e]} * m;
                    wyv[k - 3] = (v2f){eb0[e], eb1[e]} * m;
                }
            }
        } else {
            #pragma unroll
            for (int k = 3; k <= 16; ++k) {
                const int gc  = gc0 + k;
                const int gcc = min(max(gc, 0), 511);
                const float cm = ((unsigned)gc < 512u) ? 1.f : 0.f;
                const v2f mm = m * cm;
                wxv[k - 3] = (v2f){xb[grc0 * 512 + gcc], xb[grc1 * 512 + gcc]} * mm;
                wyv[k - 3] = (v2f){yb[grc0 * 512 + gcc], yb[grc1 * 512 + gcc]} * mm;
            }
        }

        v2f hx[4], hy[4], hss[4], hxy[4];
        #pragma unroll
        for (int o = 0; o < 4; ++o) {
            hx[o] = (v2f)0.f; hy[o] = (v2f)0.f;
            hss[o] = (v2f)0.f; hxy[o] = (v2f)0.f;
        }
        #pragma unroll
        for (int i = 0; i < 14; ++i) {
            const v2f xv = wxv[i], yv = wyv[i];
            const v2f ss = xv * xv + yv * yv;
            const v2f xy = xv * yv;
            #pragma unroll
            for (int o = 0; o < 4; ++o) {
                const int j = i - o;            // compile-time
                if (j < 0 || j > 10) continue;
                const float wj = wk.w[j];
                hx[o]  += wj * xv;
                hy[o]  += wj * yv;
                hss[o] += wj * ss;
                hxy[o] += wj * xy;
            }
        }
        #pragma unroll
        for (int o = 0; o < 4; ++o) {
            const int idx = (c0 + o) * HR + r;
            hst[0][idx] = hx[o];
            hst[1][idx] = hy[o];
            hst[2][idx] = hss[o];
            hst[3][idx] = hxy[o];
        }
    }
    __syncthreads();

    // ---- stage 3: vertical convs + SSIM; thread = 1 col x 2 packed rows ----
    const int c  = tid & 31;
    const int r0 = (tid >> 5) << 1;             // 0..30, even -> 16B aligned
    v2f sq[4][2];
    #pragma unroll
    for (int q = 0; q < 4; ++q) {
        const float4* p4 = (const float4*)&hst[q][c * HR + r0];
        v2f tv[14];
        #pragma unroll
        for (int kk = 0; kk < 7; ++kk) {
            const float4 v = p4[kk];
            tv[2 * kk]     = (v2f){v.x, v.y};
            tv[2 * kk + 1] = (v2f){v.z, v.w};
        }
        #pragma unroll
        for (int o = 0; o < 2; ++o) {
            v2f a = (v2f)0.f;
            #pragma unroll
            for (int j = 0; j < 11; ++j) a += wk.w[j] * tv[o + j];
            sq[q][o] = a;
        }
    }

    const float C1 = 1e-4f, C2 = 9e-4f;
    float lsum = 0.f;
    #pragma unroll
    for (int o = 0; o < 2; ++o) {
        const v2f mx = sq[0][o], my = sq[1][o];
        const v2f mx2 = mx * mx, my2 = my * my, mxy = mx * my;
        const v2f sig_sum = sq[2][o] - mx2 - my2;   // sigma_x2 + sigma_y2
        const v2f sig_xy  = sq[3][o] - mxy;
        const v2f num = (2.f * mxy + C1) * (2.f * sig_xy + C2);
        const v2f den = (mx2 + my2 + C1) * (sig_sum + C2) + 1e-12f;
        lsum += num.x * __builtin_amdgcn_rcpf(den.x)
              + num.y * __builtin_amdgcn_rcpf(den.y);
    }

    // ---- block reduction (8 waves) ----
    #pragma unroll
    for (int off = 32; off; off >>= 1) lsum += __shfl_down(lsum, off);
    if ((tid & 63) == 0) red[tid >> 6] = lsum;
    __syncthreads();
    if (tid == 0) {
        float v = 0.f;
        #pragma unroll
        for (int i = 0; i < 8; ++i) v += red[i];
        if (atomic_mode) atomicAdd(partial, v);
        else partial[(bz * GY + by) * GX + bx] = v;
    }
}

__global__ __launch_bounds__(256) void ssim_fin(const float* __restrict__ partial,
                                                float* __restrict__ out, int n)
{
    float s = 0.f;
    for (int i = threadIdx.x; i < n; i += 256) s += partial[i];
    #pragma unroll
    for (int off = 32; off; off >>= 1) s += __shfl_down(s, off);
    __shared__ float red[4];
    if ((threadIdx.x & 63) == 0) red[threadIdx.x >> 6] = s;
    __syncthreads();
    if (threadIdx.x == 0)
        out[0] = 1.0f - (red[0] + red[1] + red[2] + red[3]) * (1.0f / 16777216.0f);
}

extern "C" void kernel_launch(void* const* d_in, const int* in_sizes, int n_in,
                              void* d_out, int out_size, void* d_ws, size_t ws_size,
                              hipStream_t stream) {
    const float* x = (const float*)d_in[0];
    const float* y = (const float*)d_in[1];
    float* out = (float*)d_out;
    float* ws  = (float*)d_ws;

    W11 wk;
    double e[11], s = 0.0;
    for (int i = 0; i < 11; ++i) {
        double d = (double)i - 5.0;
        e[i] = exp(-(d * d) / 4.5);
        s += e[i];
    }
    for (int i = 0; i < 11; ++i) wk.w[i] = (float)(e[i] / s);

    const bool use_partial = ws_size >= (size_t)NPART * sizeof(float);
    if (!use_partial) hipMemsetAsync(d_ws, 0, sizeof(float), stream);

    hipLaunchKernelGGL(ssim_main, dim3(GX, GY, 64), dim3(512), 0, stream,
                       x, y, ws, wk, use_partial ? 0 : 1);
    hipLaunchKernelGGL(ssim_fin, dim3(1), dim3(256), 0, stream,
                       ws, out, use_partial ? NPART : 1);
}

// Round 8
// 250.544 us; speedup vs baseline: 3.5027x; 1.0012x over previous
//
#include <hip/hip_runtime.h>
#include <math.h>

// SSIM loss fp32, B=64 H=W=512, 11x11 Gaussian sigma=1.5, separable (w ⊗ w).
// R8 = R7 + forced ILP batching.
// R7 post-mortem: VGPR_Count=52 -> compiler serialized each quantity's LDS
// loads behind its compute (4 sequential latency chains in stage3). R8 loads
// all 28 ds_read_b128 (tvq[4][14]) before any conv math, and all 20 global
// float4 in stage2 before the window build. Occupancy cap unchanged
// (LDS 43 KB -> 3 blocks/CU x 8 waves = 24 waves; VGPR < 341 budget).

typedef float v2f __attribute__((ext_vector_type(2)));

#define TS   32
#define HR   42
#define GX   16
#define GY   8
#define NPART (64 * GY * GX)   // 8192

struct W11 { float w[11]; };

__global__ __launch_bounds__(512) void ssim_main(
    const float* __restrict__ x, const float* __restrict__ y,
    float* __restrict__ partial, W11 wk, int atomic_mode)
{
    __shared__ __align__(16) v2f hst[4][TS * HR];   // 43008 B
    __shared__ float red[8];

    const int tid = threadIdx.x;
    const int bx = blockIdx.x, by = blockIdx.y, bz = blockIdx.z;
    const float* __restrict__ xb = x + (size_t)bz * (512 * 512);
    const float* __restrict__ yb = y + (size_t)bz * (512 * 512);
    const int ox = bx * TS;
    const int oy = by * 64;
    const bool colInterior = (bx >= 1) && (bx <= 14);

    // ---- stage 2: horizontal convs of {x, y, x^2+y^2, xy}, bands packed ----
    if (tid < HR * 8) {
        const int r  = tid >> 3;
        const int c0 = (tid & 7) << 2;
        const int gr = oy - 5 + r;              // band0 input row
        const float m0 = ((unsigned)gr        < 512u) ? 1.f : 0.f;
        const float m1 = ((unsigned)(gr + 32) < 512u) ? 1.f : 0.f;
        const v2f  m  = (v2f){m0, m1};
        const int grc0 = min(max(gr, 0), 511);
        const int grc1 = min(max(gr + 32, 0), 511);
        const int gc0 = ox + c0 - 8;            // window cols k=3..16 used

        v2f wxv[14], wyv[14];
        if (colInterior) {
            const float4* px0 = (const float4*)(xb + grc0 * 512 + gc0);
            const float4* px1 = (const float4*)(xb + grc1 * 512 + gc0);
            const float4* py0 = (const float4*)(yb + grc0 * 512 + gc0);
            const float4* py1 = (const float4*)(yb + grc1 * 512 + gc0);
            // batch ALL 20 loads first (independent -> one latency window)
            float4 a[5], b[5], cc[5], d[5];
            #pragma unroll
            for (int kk = 0; kk < 5; ++kk) {
                a[kk]  = px0[kk];
                b[kk]  = px1[kk];
                cc[kk] = py0[kk];
                d[kk]  = py1[kk];
            }
            #pragma unroll
            for (int kk = 0; kk < 5; ++kk) {
                const float ea0[4] = {a[kk].x,  a[kk].y,  a[kk].z,  a[kk].w};
                const float ea1[4] = {b[kk].x,  b[kk].y,  b[kk].z,  b[kk].w};
                const float eb0[4] = {cc[kk].x, cc[kk].y, cc[kk].z, cc[kk].w};
                const float eb1[4] = {d[kk].x,  d[kk].y,  d[kk].z,  d[kk].w};
                #pragma unroll
                for (int e = 0; e < 4; ++e) {
                    const int k = kk * 4 + e;
                    if (k < 3 || k > 16) continue;
                    wxv[k - 3] = (v2f){ea0[e], ea1[e]} * m;
                    wyv[k - 3] = (v2f){eb0[e], eb1[e]} * m;
                }
            }
        } else {
            #pragma unroll
            for (int k = 3; k <= 16; ++k) {
                const int gc  = gc0 + k;
                const int gcc = min(max(gc, 0), 511);
                const float cm = ((unsigned)gc < 512u) ? 1.f : 0.f;
                const v2f mm = m * cm;
                wxv[k - 3] = (v2f){xb[grc0 * 512 + gcc], xb[grc1 * 512 + gcc]} * mm;
                wyv[k - 3] = (v2f){yb[grc0 * 512 + gcc], yb[grc1 * 512 + gcc]} * mm;
            }
        }

        v2f hx[4], hy[4], hss[4], hxy[4];
        #pragma unroll
        for (int o = 0; o < 4; ++o) {
            hx[o] = (v2f)0.f; hy[o] = (v2f)0.f;
            hss[o] = (v2f)0.f; hxy[o] = (v2f)0.f;
        }
        #pragma unroll
        for (int i = 0; i < 14; ++i) {
            const v2f xv = wxv[i], yv = wyv[i];
            const v2f ss = xv * xv + yv * yv;
            const v2f xy = xv * yv;
            #pragma unroll
            for (int o = 0; o < 4; ++o) {
                const int j = i - o;            // compile-time
                if (j < 0 || j > 10) continue;
                const float wj = wk.w[j];
                hx[o]  += wj * xv;
                hy[o]  += wj * yv;
                hss[o] += wj * ss;
                hxy[o] += wj * xy;
            }
        }
        #pragma unroll
        for (int o = 0; o < 4; ++o) {
            const int idx = (c0 + o) * HR + r;
            hst[0][idx] = hx[o];
            hst[1][idx] = hy[o];
            hst[2][idx] = hss[o];
            hst[3][idx] = hxy[o];
        }
    }
    __syncthreads();

    // ---- stage 3: batch ALL 28 b128 loads, then convs + SSIM ----
    const int c  = tid & 31;
    const int r0 = (tid >> 5) << 1;             // 0..30, even -> 16B aligned
    v2f tvq[4][14];
    #pragma unroll
    for (int q = 0; q < 4; ++q) {
        const float4* p4 = (const float4*)&hst[q][c * HR + r0];
        #pragma unroll
        for (int kk = 0; kk < 7; ++kk) {
            const float4 v = p4[kk];
            tvq[q][2 * kk]     = (v2f){v.x, v.y};
            tvq[q][2 * kk + 1] = (v2f){v.z, v.w};
        }
    }
    v2f sq[4][2];
    #pragma unroll
    for (int q = 0; q < 4; ++q) {
        #pragma unroll
        for (int o = 0; o < 2; ++o) {
            v2f a = (v2f)0.f;
            #pragma unroll
            for (int j = 0; j < 11; ++j) a += wk.w[j] * tvq[q][o + j];
            sq[q][o] = a;
        }
    }

    const float C1 = 1e-4f, C2 = 9e-4f;
    float lsum = 0.f;
    #pragma unroll
    for (int o = 0; o < 2; ++o) {
        const v2f mx = sq[0][o], my = sq[1][o];
        const v2f mx2 = mx * mx, my2 = my * my, mxy = mx * my;
        const v2f sig_sum = sq[2][o] - mx2 - my2;   // sigma_x2 + sigma_y2
        const v2f sig_xy  = sq[3][o] - mxy;
        const v2f num = (2.f * mxy + C1) * (2.f * sig_xy + C2);
        const v2f den = (mx2 + my2 + C1) * (sig_sum + C2) + 1e-12f;
        lsum += num.x * __builtin_amdgcn_rcpf(den.x)
              + num.y * __builtin_amdgcn_rcpf(den.y);
    }

    // ---- block reduction (8 waves) ----
    #pragma unroll
    for (int off = 32; off; off >>= 1) lsum += __shfl_down(lsum, off);
    if ((tid & 63) == 0) red[tid >> 6] = lsum;
    __syncthreads();
    if (tid == 0) {
        float v = 0.f;
        #pragma unroll
        for (int i = 0; i < 8; ++i) v += red[i];
        if (atomic_mode) atomicAdd(partial, v);
        else partial[(bz * GY + by) * GX + bx] = v;
    }
}

__global__ __launch_bounds__(256) void ssim_fin(const float* __restrict__ partial,
                                                float* __restrict__ out, int n)
{
    float s = 0.f;
    for (int i = threadIdx.x; i < n; i += 256) s += partial[i];
    #pragma unroll
    for (int off = 32; off; off >>= 1) s += __shfl_down(s, off);
    __shared__ float red[4];
    if ((threadIdx.x & 63) == 0) red[threadIdx.x >> 6] = s;
    __syncthreads();
    if (threadIdx.x == 0)
        out[0] = 1.0f - (red[0] + red[1] + red[2] + red[3]) * (1.0f / 16777216.0f);
}

extern "C" void kernel_launch(void* const* d_in, const int* in_sizes, int n_in,
                              void* d_out, int out_size, void* d_ws, size_t ws_size,
                              hipStream_t stream) {
    const float* x = (const float*)d_in[0];
    const float* y = (const float*)d_in[1];
    float* out = (float*)d_out;
    float* ws  = (float*)d_ws;

    W11 wk;
    double e[11], s = 0.0;
    for (int i = 0; i < 11; ++i) {
        double d = (double)i - 5.0;
        e[i] = exp(-(d * d) / 4.5);
        s += e[i];
    }
    for (int i = 0; i < 11; ++i) wk.w[i] = (float)(e[i] / s);

    const bool use_partial = ws_size >= (size_t)NPART * sizeof(float);
    if (!use_partial) hipMemsetAsync(d_ws, 0, sizeof(float), stream);

    hipLaunchKernelGGL(ssim_main, dim3(GX, GY, 64), dim3(512), 0, stream,
                       x, y, ws, wk, use_partial ? 0 : 1);
    hipLaunchKernelGGL(ssim_fin, dim3(1), dim3(256), 0, stream,
                       ws, out, use_partial ? NPART : 1);
}